// Round 2
// baseline (188.512 us; speedup 1.0000x reference)
//
#include <hip/hip_runtime.h>
#include <hip/hip_fp16.h>

// dot_attention: out[b,n] = exp(diag*s - lse_n), s = (D/2)^-0.5 = 1/16.
// B=4, N=4096, D=512. Inputs fp32, output fp32.
// Scores |.| <~ 9 -> sum exp directly in fp32, no running max.
// CDNA4 has no fp32 MFMA -> convert to fp16 (2^-11 rel) and use
// mfma_f32_16x16x32_f16; score abs err ~1e-3 -> out err ~1e-4 << 4.4e-4 thr.

typedef _Float16 f16x8 __attribute__((ext_vector_type(8)));  // MFMA A/B frag (4 VGPR)
typedef float    f32x4 __attribute__((ext_vector_type(4)));  // MFMA C/D frag

#define NB 4
#define NN 4096
#define ND 512
#define SCALE 0.0625f
#define NROWS (NB * NN)            // 16384
// LDS tile: 64 kv rows x 512 fp16 = 64KB; row r at byte r*1024 + (r&7)*16
// so b128 frag reads hit the 8-lanes-per-4-bank-group floor (no excess conflict).
#define TILE_BYTES 65664

__device__ __forceinline__ void gld16(const void* g, void* l) {
    __builtin_amdgcn_global_load_lds(
        (const __attribute__((address_space(1))) unsigned int*)g,
        (__attribute__((address_space(3))) unsigned int*)l, 16, 0, 0);
}

__device__ __forceinline__ f16x8 cvt8(float4 a, float4 b) {
    f16x8 r;
    r[0] = (_Float16)a.x; r[1] = (_Float16)a.y; r[2] = (_Float16)a.z; r[3] = (_Float16)a.w;
    r[4] = (_Float16)b.x; r[5] = (_Float16)b.y; r[6] = (_Float16)b.z; r[7] = (_Float16)b.w;
    return r;
}

// ---- kernel 1: kv fp32 -> fp16 copy (for MFMA B) + diag dot (fp32 exact path)
__launch_bounds__(256)
__global__ void convert_kernel(const float* __restrict__ q,
                               const float* __restrict__ kv,
                               _Float16* __restrict__ kvh,
                               float* __restrict__ diag) {
    const int row  = blockIdx.x * 4 + (threadIdx.x >> 6);
    const int lane = threadIdx.x & 63;

    const float4* kr = (const float4*)(kv + (size_t)row * ND) + lane * 2;
    const float4* qr = (const float4*)(q  + (size_t)row * ND) + lane * 2;
    float4 k0 = kr[0], k1 = kr[1];
    float4 q0 = qr[0], q1 = qr[1];

    *(f16x8*)(kvh + (size_t)row * ND + lane * 8) = cvt8(k0, k1);

    float dot = q0.x * k0.x;
    dot = fmaf(q0.y, k0.y, dot); dot = fmaf(q0.z, k0.z, dot); dot = fmaf(q0.w, k0.w, dot);
    dot = fmaf(q1.x, k1.x, dot); dot = fmaf(q1.y, k1.y, dot);
    dot = fmaf(q1.z, k1.z, dot); dot = fmaf(q1.w, k1.w, dot);

    dot += __shfl_xor(dot, 1, 64);
    dot += __shfl_xor(dot, 2, 64);
    dot += __shfl_xor(dot, 4, 64);
    dot += __shfl_xor(dot, 8, 64);
    dot += __shfl_xor(dot, 16, 64);
    dot += __shfl_xor(dot, 32, 64);
    if (lane == 0) diag[row] = dot;
}

// ---- kernel 2: per-row sum of exp(score) over a 1024-column split.
// grid (16: b*4+cs, 16: rowblock), 256 threads = 4 waves, 1 block/CU.
// Wave: 64 q-rows, A-frags (fp16, converted from fp32 on load) register-resident.
// kv16 tiles (64 rows) staged via global_load_lds into double-buffered LDS.
__launch_bounds__(256, 1)
__global__ void lse_partial_kernel(const float* __restrict__ q,
                                   const _Float16* __restrict__ kvh,
                                   float* __restrict__ partial) {
    __shared__ char sbuf[2][TILE_BYTES];

    const int bc = blockIdx.x;          // b*4 + cs  (fastest-varying -> XCD spread)
    const int b  = bc >> 2;
    const int cs = bc & 3;
    const int rb = blockIdx.y;
    const int tid  = threadIdx.x;
    const int wid  = tid >> 6;
    const int lane = tid & 63;
    const int l15  = lane & 15;
    const int quad = lane >> 4;

    const int row0 = rb * 256 + wid * 64;    // wave's first q-row (in batch)

    // ---- A fragments: q fp32 -> fp16, A[m = lane&15][k = quad*8+j]
    f16x8 Af[4][16];
    #pragma unroll
    for (int m = 0; m < 4; ++m) {
        const float* qrow = q + ((size_t)(b * NN + row0 + m * 16 + l15)) * ND + quad * 8;
        #pragma unroll
        for (int k = 0; k < 16; ++k) {
            float4 u0 = *(const float4*)(qrow + k * 32);
            float4 u1 = *(const float4*)(qrow + k * 32 + 4);
            Af[m][k] = cvt8(u0, u1);
        }
    }

    float lacc[4][4];
    #pragma unroll
    for (int m = 0; m < 4; ++m)
        #pragma unroll
        for (int j = 0; j < 4; ++j)
            lacc[m][j] = 0.f;

    // per-nf LDS base for B-frag reads: row = nf*16 + l15
    unsigned base_nf[4];
    #pragma unroll
    for (int nf = 0; nf < 4; ++nf)
        base_nf[nf] = (unsigned)((nf * 16 + l15) * 1024 + (l15 & 7) * 16 + quad * 16);

    const _Float16* kvbase = kvh + ((size_t)(b * NN + cs * 1024)) * ND;

    // stage tile `it` into sbuf[buf]: 16 rows per wave, 1KB (64 lanes x 16B) per row
    #define STAGE(it_, buf_)                                                         \
        do {                                                                         \
            const _Float16* gb_ = kvbase + (size_t)(it_) * 64 * ND;                  \
            char* lb_ = sbuf[buf_];                                                  \
            _Pragma("unroll")                                                        \
            for (int p_ = 0; p_ < 16; ++p_) {                                        \
                int r_ = wid * 16 + p_;                                              \
                gld16(gb_ + (size_t)r_ * ND + lane * 8,                              \
                      lb_ + r_ * 1024 + ((r_ & 7) << 4));                            \
            }                                                                        \
        } while (0)

    STAGE(0, 0);
    int buf = 0;

    for (int it = 0; it < 16; ++it) {
        __syncthreads();                      // drains tile-`it` DMA for all waves
        if (it + 1 < 16) STAGE(it + 1, buf ^ 1);

        const char* lb = sbuf[buf];
        f32x4 acc[4][4];
        #pragma unroll
        for (int m = 0; m < 4; ++m)
            #pragma unroll
            for (int nf = 0; nf < 4; ++nf)
                acc[m][nf] = (f32x4){0.f, 0.f, 0.f, 0.f};

        #pragma unroll
        for (int kt = 0; kt < 16; ++kt) {
            f16x8 bf[4];
            #pragma unroll
            for (int nf = 0; nf < 4; ++nf)
                bf[nf] = *(const f16x8*)(lb + base_nf[nf] + kt * 64);
            #pragma unroll
            for (int nf = 0; nf < 4; ++nf)
                #pragma unroll
                for (int m = 0; m < 4; ++m)
                    acc[m][nf] = __builtin_amdgcn_mfma_f32_16x16x32_f16(
                        Af[m][kt], bf[nf], acc[m][nf], 0, 0, 0);
        }

        // C/D: col = lane&15 (kv col), row = quad*4 + j (q row). Fold exp into lacc.
        #pragma unroll
        for (int m = 0; m < 4; ++m)
            #pragma unroll
            for (int nf = 0; nf < 4; ++nf)
                #pragma unroll
                for (int j = 0; j < 4; ++j)
                    lacc[m][j] += __expf(acc[m][nf][j] * SCALE);

        buf ^= 1;
    }

    // reduce over the 16 columns held across l15 lanes
    #pragma unroll
    for (int m = 0; m < 4; ++m)
        #pragma unroll
        for (int j = 0; j < 4; ++j) {
            float v = lacc[m][j];
            v += __shfl_xor(v, 1, 64);
            v += __shfl_xor(v, 2, 64);
            v += __shfl_xor(v, 4, 64);
            v += __shfl_xor(v, 8, 64);
            if (l15 == 0)
                partial[(size_t)cs * NROWS + b * NN + row0 + m * 16 + quad * 4 + j] = v;
        }
}

// ---- kernel 3: out = exp(diag*s) / sum_cs partial
__launch_bounds__(256)
__global__ void finalize_kernel(const float* __restrict__ partial,
                                const float* __restrict__ diag,
                                float* __restrict__ out) {
    const int idx = blockIdx.x * 256 + threadIdx.x;
    float l = partial[idx] + partial[NROWS + idx] +
              partial[2 * NROWS + idx] + partial[3 * NROWS + idx];
    out[idx] = __expf(diag[idx] * SCALE) / l;
}

extern "C" void kernel_launch(void* const* d_in, const int* in_sizes, int n_in,
                              void* d_out, int out_size, void* d_ws, size_t ws_size,
                              hipStream_t stream) {
    const float* q  = (const float*)d_in[0];
    const float* kv = (const float*)d_in[1];
    float* out = (float*)d_out;

    // ws layout: kvh fp16 [16MB] | partial f32[4][16384] (256KB) | diag f32[16384] (64KB)
    _Float16* kvh   = (_Float16*)d_ws;
    float* partial  = (float*)((char*)d_ws + (size_t)NROWS * ND * 2);
    float* diag     = partial + 4 * NROWS;

    convert_kernel<<<NROWS / 4, 256, 0, stream>>>(q, kv, kvh, diag);
    lse_partial_kernel<<<dim3(16, 16), 256, 0, stream>>>(q, kvh, partial);
    finalize_kernel<<<NROWS / 256, 256, 0, stream>>>(partial, diag, out);
}

// Round 3
// 168.417 us; speedup vs baseline: 1.1193x; 1.1193x over previous
//
#include <hip/hip_runtime.h>
#include <hip/hip_fp16.h>

// dot_attention: out[b,n] = exp(diag*s - lse_n), s = (D/2)^-0.5 = 1/16.
// B=4, N=4096, D=512. Inputs fp32, output fp32.
// Scores |.| <~ 9 -> sum exp directly in fp32, no running max.
// No fp32 MFMA on CDNA4 -> fp16 convert + mfma_f32_16x16x32_f16 (absmax ~1.2e-4).
//
// R3: occupancy fix. 32 rows/wave (Af=128 VGPR -> 2 waves/SIMD), 32-row kv tiles
// at 1040B pitch (bank-conflict-free b128, no row overlap), dbuf = 65 KB LDS ->
// 2 blocks/CU, 8 waves/CU. Staggered blocks hide barrier/DMA drains.

typedef _Float16 f16x8 __attribute__((ext_vector_type(8)));  // MFMA A/B frag (4 VGPR)
typedef float    f32x4 __attribute__((ext_vector_type(4)));  // MFMA C/D frag

#define NB 4
#define NN 4096
#define ND 512
#define SCALE 0.0625f
#define NROWS (NB * NN)            // 16384
#define TROWS 32                   // kv rows per LDS tile
#define RPITCH 1040                // 1024 data + 16 pad; 260 banks ≡ 4 mod 32
#define TBYTES (TROWS * RPITCH)    // 33280

__device__ __forceinline__ void gld16(const void* g, void* l) {
    __builtin_amdgcn_global_load_lds(
        (const __attribute__((address_space(1))) unsigned int*)g,
        (__attribute__((address_space(3))) unsigned int*)l, 16, 0, 0);
}

__device__ __forceinline__ f16x8 cvt8(float4 a, float4 b) {
    f16x8 r;
    r[0] = (_Float16)a.x; r[1] = (_Float16)a.y; r[2] = (_Float16)a.z; r[3] = (_Float16)a.w;
    r[4] = (_Float16)b.x; r[5] = (_Float16)b.y; r[6] = (_Float16)b.z; r[7] = (_Float16)b.w;
    return r;
}

// ---- kernel 1: kv fp32 -> fp16 copy (for MFMA B) + diag dot (fp32 exact path)
__launch_bounds__(256)
__global__ void convert_kernel(const float* __restrict__ q,
                               const float* __restrict__ kv,
                               _Float16* __restrict__ kvh,
                               float* __restrict__ diag) {
    const int row  = blockIdx.x * 4 + (threadIdx.x >> 6);
    const int lane = threadIdx.x & 63;

    const float4* kr = (const float4*)(kv + (size_t)row * ND) + lane * 2;
    const float4* qr = (const float4*)(q  + (size_t)row * ND) + lane * 2;
    float4 k0 = kr[0], k1 = kr[1];
    float4 q0 = qr[0], q1 = qr[1];

    *(f16x8*)(kvh + (size_t)row * ND + lane * 8) = cvt8(k0, k1);

    float dot = q0.x * k0.x;
    dot = fmaf(q0.y, k0.y, dot); dot = fmaf(q0.z, k0.z, dot); dot = fmaf(q0.w, k0.w, dot);
    dot = fmaf(q1.x, k1.x, dot); dot = fmaf(q1.y, k1.y, dot);
    dot = fmaf(q1.z, k1.z, dot); dot = fmaf(q1.w, k1.w, dot);

    dot += __shfl_xor(dot, 1, 64);
    dot += __shfl_xor(dot, 2, 64);
    dot += __shfl_xor(dot, 4, 64);
    dot += __shfl_xor(dot, 8, 64);
    dot += __shfl_xor(dot, 16, 64);
    dot += __shfl_xor(dot, 32, 64);
    if (lane == 0) diag[row] = dot;
}

// ---- kernel 2: per-row sum of exp(score) over a 1024-column split.
// grid (16: b*4+cs, 32: rowblock) = 512 blocks, 256 threads = 4 waves,
// 2 blocks/CU (65 KB LDS), 2 waves/SIMD (<=256 VGPR).
// Wave: 32 q-rows, A-frags (fp16) register-resident (128 VGPR).
// kv tiles: 32 rows, staged via global_load_lds, rows at 1040 B pitch so
// b128 frag reads hit the 8-cycle wave64 floor (rows spread 8 bank-groups).
__launch_bounds__(256, 2)
__global__ void lse_partial_kernel(const float* __restrict__ q,
                                   const _Float16* __restrict__ kvh,
                                   float* __restrict__ partial) {
    __shared__ char sbuf[2][TBYTES];

    const int bc = blockIdx.x;          // b*4 + cs
    const int b  = bc >> 2;
    const int cs = bc & 3;
    const int rb = blockIdx.y;
    const int tid  = threadIdx.x;
    const int wid  = tid >> 6;
    const int lane = tid & 63;
    const int l15  = lane & 15;
    const int quad = lane >> 4;

    const int row0 = rb * 128 + wid * 32;    // wave's first q-row (in batch)

    // ---- A fragments: q fp32 -> fp16, A[row = lane&15][k = quad*8+j]
    f16x8 Af[2][16];
    #pragma unroll
    for (int m = 0; m < 2; ++m) {
        const float* qrow = q + ((size_t)(b * NN + row0 + m * 16 + l15)) * ND + quad * 8;
        #pragma unroll
        for (int k = 0; k < 16; ++k) {
            float4 u0 = *(const float4*)(qrow + k * 32);
            float4 u1 = *(const float4*)(qrow + k * 32 + 4);
            Af[m][k] = cvt8(u0, u1);
        }
    }

    float lacc[2][4];
    #pragma unroll
    for (int m = 0; m < 2; ++m)
        #pragma unroll
        for (int j = 0; j < 4; ++j)
            lacc[m][j] = 0.f;

    // B-frag LDS base: row = nf*16 + l15, chunk = quad
    unsigned base_nf[2];
    #pragma unroll
    for (int nf = 0; nf < 2; ++nf)
        base_nf[nf] = (unsigned)((nf * 16 + l15) * RPITCH + quad * 16);

    const _Float16* kvbase = kvh + ((size_t)(b * NN + cs * 1024)) * ND;

    // stage tile `it` into sbuf[buf]: 8 rows per wave, 1 KB DMA per row
    #define STAGE(it_, buf_)                                                 \
        do {                                                                 \
            const _Float16* gb_ = kvbase + (size_t)(it_) * TROWS * ND;       \
            char* lb_ = sbuf[buf_];                                          \
            _Pragma("unroll")                                                \
            for (int p_ = 0; p_ < 8; ++p_) {                                 \
                int r_ = wid * 8 + p_;                                       \
                gld16(gb_ + (size_t)r_ * ND + lane * 8, lb_ + r_ * RPITCH);  \
            }                                                                \
        } while (0)

    STAGE(0, 0);
    int buf = 0;

    for (int it = 0; it < 32; ++it) {
        __syncthreads();                      // drains tile-`it` DMA
        if (it + 1 < 32) STAGE(it + 1, buf ^ 1);

        const char* lb = sbuf[buf];
        f32x4 acc[2][2];
        #pragma unroll
        for (int m = 0; m < 2; ++m)
            #pragma unroll
            for (int nf = 0; nf < 2; ++nf)
                acc[m][nf] = (f32x4){0.f, 0.f, 0.f, 0.f};

        #pragma unroll
        for (int kt = 0; kt < 16; ++kt) {
            f16x8 bf[2];
            #pragma unroll
            for (int nf = 0; nf < 2; ++nf)
                bf[nf] = *(const f16x8*)(lb + base_nf[nf] + kt * 64);
            #pragma unroll
            for (int nf = 0; nf < 2; ++nf)
                #pragma unroll
                for (int m = 0; m < 2; ++m)
                    acc[m][nf] = __builtin_amdgcn_mfma_f32_16x16x32_f16(
                        Af[m][kt], bf[nf], acc[m][nf], 0, 0, 0);
        }

        // C/D: col = lane&15 (kv col), row = quad*4 + j (q row). Fold exp.
        #pragma unroll
        for (int m = 0; m < 2; ++m)
            #pragma unroll
            for (int nf = 0; nf < 2; ++nf)
                #pragma unroll
                for (int j = 0; j < 4; ++j)
                    lacc[m][j] += __expf(acc[m][nf][j] * SCALE);

        buf ^= 1;
    }

    // reduce over the 16 columns held across l15 lanes
    #pragma unroll
    for (int m = 0; m < 2; ++m)
        #pragma unroll
        for (int j = 0; j < 4; ++j) {
            float v = lacc[m][j];
            v += __shfl_xor(v, 1, 64);
            v += __shfl_xor(v, 2, 64);
            v += __shfl_xor(v, 4, 64);
            v += __shfl_xor(v, 8, 64);
            if (l15 == 0)
                partial[(size_t)cs * NROWS + b * NN + row0 + m * 16 + quad * 4 + j] = v;
        }
}

// ---- kernel 3: out = exp(diag*s) / sum_cs partial
__launch_bounds__(256)
__global__ void finalize_kernel(const float* __restrict__ partial,
                                const float* __restrict__ diag,
                                float* __restrict__ out) {
    const int idx = blockIdx.x * 256 + threadIdx.x;
    float l = partial[idx] + partial[NROWS + idx] +
              partial[2 * NROWS + idx] + partial[3 * NROWS + idx];
    out[idx] = __expf(diag[idx] * SCALE) / l;
}

extern "C" void kernel_launch(void* const* d_in, const int* in_sizes, int n_in,
                              void* d_out, int out_size, void* d_ws, size_t ws_size,
                              hipStream_t stream) {
    const float* q  = (const float*)d_in[0];
    const float* kv = (const float*)d_in[1];
    float* out = (float*)d_out;

    // ws layout: kvh fp16 [16MB] | partial f32[4][16384] (256KB) | diag f32[16384]
    _Float16* kvh   = (_Float16*)d_ws;
    float* partial  = (float*)((char*)d_ws + (size_t)NROWS * ND * 2);
    float* diag     = partial + 4 * NROWS;

    convert_kernel<<<NROWS / 4, 256, 0, stream>>>(q, kv, kvh, diag);
    lse_partial_kernel<<<dim3(16, 32), 256, 0, stream>>>(q, kvh, partial);
    finalize_kernel<<<NROWS / 256, 256, 0, stream>>>(partial, diag, out);
}